// Round 8
// baseline (803.419 us; speedup 1.0000x reference)
//
#include <hip/hip_runtime.h>
#include <math.h>

// 2-layer ReLU RNN, B=256, T=1000 (input 800 + zero pad), H=128, F=5.
// R8: TWO batch elements per block (128 blocks x 1024 thr = 16 waves).
// R7 post-mortem: VALUBusy is ~2x inflated (gfx94x derived formula vs
// SIMD-32 reality) -> real step = ~370 cyc issue + ~870 cyc latency/barrier.
// Fix: double independent work per barrier interval. Per elem 8 waves:
//   gAB (4 wv): h0[s] = relu(Whh0.h0[s-1] + Wih0.x[s] + b0)   and
//               A[s-1] = Wih1.h0[s-1] + b1   (one shared h0 read, 64 fdot2)
//   gC  (4 wv): h1[s-2] = relu(A[s-2] + Whh1.h1[s-3])  + batched y-dots
// role = (wv ^ (wv>>2)) & 1 keeps 2 gAB + 2 gC per SIMD under both wv%4 and
// wv/4 wave->SIMD mappings. 8x8 tiles, XOR-linear row map, all-DPP 16-lane
// reduction, ONE barrier/step (R2/R7-verified). x stored fp16 -> fdot2.
// No global ops inside the step loop.

#define TT    1000
#define TIN   800
#define HD    128
#define NF    5
#define BATCH 256

typedef _Float16 h16x2 __attribute__((ext_vector_type(2)));
typedef _Float16 h16x8 __attribute__((ext_vector_type(8)));

template<int CTRL>
__device__ __forceinline__ float dpp_mov(float v) {
    union { float f; int i; } u, r;
    u.f = v;
    r.i = __builtin_amdgcn_update_dpp(0, u.i, CTRL, 0xF, 0xF, true);
    return r.f;
}

__device__ __forceinline__ float red16(float a[8]) {
    a[0] += dpp_mov<0xB1>(a[4]);   // xor1
    a[1] += dpp_mov<0xB1>(a[5]);
    a[2] += dpp_mov<0xB1>(a[6]);
    a[3] += dpp_mov<0xB1>(a[7]);
    a[0] += dpp_mov<0x4E>(a[2]);   // xor2
    a[1] += dpp_mov<0x4E>(a[3]);
    a[0] += dpp_mov<0x140>(a[1]);  // xor15 (row_mirror)
    a[0] += dpp_mov<0x128>(a[0]);  // xor8  (row_ror:8)
    return a[0];
}

__global__ __launch_bounds__(1024, 4) void rnn_dual(
    const float* __restrict__ x,        // [256,800,5]
    const float* __restrict__ h_state,  // [2,256,128]
    const float* __restrict__ w_ih0,    // [128,5]
    const float* __restrict__ w_hh0,    // [128,128]
    const float* __restrict__ b_ih0,    // [128]
    const float* __restrict__ b_hh0,    // [128]
    const float* __restrict__ w_ih1,    // [128,128]
    const float* __restrict__ w_hh1,    // [128,128]
    const float* __restrict__ b_ih1,    // [128]
    const float* __restrict__ b_hh1,    // [128]
    const float* __restrict__ w_out,    // [1,128]
    const float* __restrict__ b_out,    // [1]
    float* __restrict__ out)            // [204800 y] ++ [65536 final states]
{
    __shared__ __align__(16) _Float16 x_h[2][TIN * 8];   // 25.6 KB (pads 0)
    __shared__ __align__(16) _Float16 h0h[2][2][HD];
    __shared__ __align__(16) _Float16 h1h[2][2][HD];
    __shared__ float A_f[2][2][HD];                      // pre-act incl. b1
    __shared__ __align__(16) _Float16 ring[2][16][HD];   // h1 history fp16
    __shared__ float wout_lds[HD];
    __shared__ float y_lds[2][TIN];

    const int tid  = threadIdx.x;
    const int bb   = blockIdx.x;               // pair index: elems 2bb, 2bb+1
    const int wv   = tid >> 6;
    const int lane = tid & 63;
    const int role = (wv ^ (wv >> 2)) & 1;     // 0 = gAB, 1 = gC
    const int e    = (wv >> 1) & 1;            // elem within pair
    const int sub  = ((wv >> 3) << 1) | ((wv >> 2) & 1);  // 0..3 in group
    const int it   = (sub << 6) | lane;        // 0..255 within (role,e)
    const int c    = it & 15;
    const int rg   = it >> 4;
    const int g    = (4 * (c & 1)) ^ (2 * ((c >> 1) & 1)) ^ (7 * ((c >> 2) & 1));
    const int row  = rg * 8 + g;
    const bool writer = (c & 8) == 0;
    const int be   = 2 * bb + e;               // global batch element

    // ---- stage x (fp16, stride 8, pads zero) + h-state + w_out ----
    {
        _Float16* xf = &x_h[0][0];
        for (int i = tid; i < 2 * TIN * 8; i += 1024) xf[i] = (_Float16)0.f;
    }
    __syncthreads();
    for (int i = tid; i < 2 * TIN * NF; i += 1024) {
        const int ee = (i < TIN * NF) ? 0 : 1;
        const int j  = i - ee * TIN * NF;
        const int t  = j / 5, f = j - 5 * t;
        x_h[ee][t * 8 + f] = (_Float16)x[(2 * bb + ee) * (TIN * NF) + j];
    }
    if (tid < 2 * HD) {
        const int ee = tid >> 7, k = tid & 127;
        h0h[ee][0][k] = (_Float16)h_state[(2 * bb + ee) * HD + k];
        h1h[ee][0][k] = (_Float16)h_state[BATCH * HD + (2 * bb + ee) * HD + k];
    } else if (tid < 3 * HD) {
        wout_lds[tid - 2 * HD] = w_out[tid - 2 * HD];
    }

    // ---- resident weights (fp16 pairs), 8x8 tile rows rg*8+(j^g) ----
    h16x2 wA[8][4], wB[8][4];
    h16x2 wx0 = {0,0}, wx1 = {0,0}, wx2 = {0,0};
    float bias0 = 0.f, bias1 = 0.f;
    if (role == 0) {
        #pragma unroll
        for (int j = 0; j < 8; ++j) {
            const float* pa = w_hh0 + (rg * 8 + (j ^ g)) * HD + c * 8;
            const float* pb = w_ih1 + (rg * 8 + (j ^ g)) * HD + c * 8;
            #pragma unroll
            for (int t = 0; t < 4; ++t) {
                h16x2 a = { (_Float16)pa[2 * t], (_Float16)pa[2 * t + 1] };
                h16x2 b = { (_Float16)pb[2 * t], (_Float16)pb[2 * t + 1] };
                wA[j][t] = a; wB[j][t] = b;
            }
        }
        wx0[0] = (_Float16)w_ih0[row * NF + 0];
        wx0[1] = (_Float16)w_ih0[row * NF + 1];
        wx1[0] = (_Float16)w_ih0[row * NF + 2];
        wx1[1] = (_Float16)w_ih0[row * NF + 3];
        wx2[0] = (_Float16)w_ih0[row * NF + 4];
        bias0 = b_ih0[row] + b_hh0[row];
        bias1 = b_ih1[row] + b_hh1[row];
    } else {
        #pragma unroll
        for (int j = 0; j < 8; ++j) {
            const float* pa = w_hh1 + (rg * 8 + (j ^ g)) * HD + c * 8;
            #pragma unroll
            for (int t = 0; t < 4; ++t) {
                h16x2 a = { (_Float16)pa[2 * t], (_Float16)pa[2 * t + 1] };
                wA[j][t] = a;
            }
        }
    }
    const float bout = b_out[0];

    float fin0 = 0.f, fin1 = 0.f;

    __syncthreads();

    #pragma unroll 2
    for (int s = 0; s < TT + 2; ++s) {
        const int p = s & 1;
        const int q = p ^ 1;

        if (role == 0) {
            // gAB: h0[s] and A[s-1] off one h0[s-1] read
            if (s <= TT) {
                h16x8 hv = *(const h16x8*)(&h0h[e][p][c * 8]);
                h16x2 hp0 = { hv[0], hv[1] }, hp1 = { hv[2], hv[3] };
                h16x2 hp2 = { hv[4], hv[5] }, hp3 = { hv[6], hv[7] };
                float a[8], b[8];
                #pragma unroll
                for (int j = 0; j < 8; ++j) {
                    float aj = __builtin_amdgcn_fdot2(wA[j][0], hp0, 0.f, false);
                    aj = __builtin_amdgcn_fdot2(wA[j][1], hp1, aj, false);
                    aj = __builtin_amdgcn_fdot2(wA[j][2], hp2, aj, false);
                    aj = __builtin_amdgcn_fdot2(wA[j][3], hp3, aj, false);
                    a[j] = aj;
                    float bj = __builtin_amdgcn_fdot2(wB[j][0], hp0, 0.f, false);
                    bj = __builtin_amdgcn_fdot2(wB[j][1], hp1, bj, false);
                    bj = __builtin_amdgcn_fdot2(wB[j][2], hp2, bj, false);
                    bj = __builtin_amdgcn_fdot2(wB[j][3], hp3, bj, false);
                    b[j] = bj;
                }
                float ra = red16(a);
                float rb = red16(b);
                float xc = 0.f;
                if (s < TIN) {
                    h16x8 xv = *(const h16x8*)(&x_h[e][s * 8]);
                    h16x2 xp0 = { xv[0], xv[1] }, xp1 = { xv[2], xv[3] };
                    h16x2 xp2 = { xv[4], xv[5] };
                    xc = __builtin_amdgcn_fdot2(wx2, xp2, 0.f, false);
                    xc = __builtin_amdgcn_fdot2(wx1, xp1, xc,  false);
                    xc = __builtin_amdgcn_fdot2(wx0, xp0, xc,  false);
                }
                float v0 = fmaxf(ra + bias0 + xc, 0.f);
                float v1 = rb + bias1;
                if (writer) {
                    if (s < TT) {
                        h0h[e][q][row] = (_Float16)v0;
                        if (s == TT - 1) fin0 = v0;
                    }
                    A_f[e][q][row] = v1;
                }
            }
        } else {
            // gC: h1[s-2] = relu(A[s-2] + Whh1.h1[s-3])
            if (s >= 2) {
                const int u = s - 2;
                float pre = A_f[e][p][row];
                h16x8 hv = *(const h16x8*)(&h1h[e][p][c * 8]);
                h16x2 hp0 = { hv[0], hv[1] }, hp1 = { hv[2], hv[3] };
                h16x2 hp2 = { hv[4], hv[5] }, hp3 = { hv[6], hv[7] };
                float a[8];
                #pragma unroll
                for (int j = 0; j < 8; ++j) {
                    float aj = __builtin_amdgcn_fdot2(wA[j][0], hp0, 0.f, false);
                    aj = __builtin_amdgcn_fdot2(wA[j][1], hp1, aj, false);
                    aj = __builtin_amdgcn_fdot2(wA[j][2], hp2, aj, false);
                    aj = __builtin_amdgcn_fdot2(wA[j][3], hp3, aj, false);
                    a[j] = aj;
                }
                float ra = red16(a);
                float v = fmaxf(ra + pre, 0.f);
                if (writer) {
                    _Float16 vh = (_Float16)v;
                    h1h[e][q][row] = vh;
                    if (u < TIN) ring[e][u & 15][row] = vh;
                    if (u == TT - 1) fin1 = v;
                }
            }
            // batched y-dots: 8 sigmoids per visit, every 8th step
            if (s >= 10 && s <= 802 && ((s - 2) & 7) == 0) {
                const int u  = (s - 10) + (it >> 5);
                const int l5 = it & 31;
                const _Float16* hr = ring[e][u & 15];
                float v = (float)hr[l5      ] * wout_lds[l5      ]
                        + (float)hr[l5 + 32] * wout_lds[l5 + 32]
                        + (float)hr[l5 + 64] * wout_lds[l5 + 64]
                        + (float)hr[l5 + 96] * wout_lds[l5 + 96];
                v += __shfl_xor(v, 16, 64);
                v += __shfl_xor(v,  8, 64);
                v += __shfl_xor(v,  4, 64);
                v += __shfl_xor(v,  2, 64);
                v += __shfl_xor(v,  1, 64);
                if (l5 == 0) y_lds[e][u] = 1.f / (1.f + expf(-(v + bout)));
            }
        }
        __syncthreads();
    }

    // ---- epilogue: single global dump (both elems) ----
    for (int i = tid; i < 2 * TIN; i += 1024) {
        const int ee = (i < TIN) ? 0 : 1;
        const int t  = i - ee * TIN;
        out[(2 * bb + ee) * TIN + t] = y_lds[ee][t];
    }
    if (role == 0 && writer)
        out[TIN * BATCH + be * HD + row] = fin0;
    if (role == 1 && writer)
        out[TIN * BATCH + BATCH * HD + be * HD + row] = fin1;
}

extern "C" void kernel_launch(void* const* d_in, const int* in_sizes, int n_in,
                              void* d_out, int out_size, void* d_ws, size_t ws_size,
                              hipStream_t stream) {
    (void)in_sizes; (void)n_in; (void)d_ws; (void)ws_size; (void)out_size;
    rnn_dual<<<dim3(BATCH / 2), dim3(1024), 0, stream>>>(
        (const float*)d_in[0],  (const float*)d_in[1],
        (const float*)d_in[2],  (const float*)d_in[3],
        (const float*)d_in[4],  (const float*)d_in[5],
        (const float*)d_in[6],  (const float*)d_in[7],
        (const float*)d_in[8],  (const float*)d_in[9],
        (const float*)d_in[10], (const float*)d_in[11],
        (float*)d_out);
}

// Round 9
// 668.588 us; speedup vs baseline: 1.2017x; 1.2017x over previous
//
#include <hip/hip_runtime.h>
#include <math.h>

// 2-layer ReLU RNN, B=256, T=1000 (input 800 + zero pad), H=128, F=5.
// R9: barrier-free flag-pipelined dataflow. 256 blocks x 256 thr = 4 waves,
// one per SIMD, each a pipeline stage (R7/R8 post-mortem: the per-step
// 12-wave __syncthreads convoy was ~900 of 1260 cyc/step):
//   e0: h0[s] = relu(Whh0.h0[s-1] + xw[s] + b0)        (in-wave recurrence)
//   e1: A[t]  = Wih1.h0[t] + b1                         (h0 ring consumer)
//   e2: h1[t] = relu(Whh1.h1[t-1] + A[t])               (in-wave recurrence)
//   e3: xw[t] = Wih0.x[t] produced 24 steps ahead; y[t] = sigmoid(wo.h1[t])
// Sync: LDS rings (depth 16/32) + monotone counters. Producer: data write ->
// threadfence_block -> flag. Consumer: volatile poll -> compiler barrier ->
// read. Same-wave ring re-read relies on in-order DS pipe. Backpressure
// polls amortized (every 8/16 steps). Bounded-buffer DAG => deadlock-free.
// Per lane (qd=l>>2, cc=l&3): rows 8qd..+7, cols 32cc..+31; weights fp16 in
// 128 VGPRs (launch_bounds(256,1) -> 512-VGPR budget, 1 wave/SIMD).
// Quad allreduce via DPP quad_perm 0xB1 (xor1) + 0x4E (xor2), R2-verified.

#define TT    1000
#define TIN   800
#define HD    128
#define NF    5
#define BATCH 256

typedef float f32x4v __attribute__((ext_vector_type(4)));
typedef _Float16 h16x2 __attribute__((ext_vector_type(2)));
typedef _Float16 h16x8 __attribute__((ext_vector_type(8)));

template<int CTRL>
__device__ __forceinline__ float dpp_mov(float v) {
    union { float f; int i; } u, r;
    u.f = v;
    r.i = __builtin_amdgcn_update_dpp(0, u.i, CTRL, 0xF, 0xF, true);
    return r.f;
}

__global__ __launch_bounds__(256, 1) void rnn_pipe(
    const float* __restrict__ x,        // [256,800,5]
    const float* __restrict__ h_state,  // [2,256,128]
    const float* __restrict__ w_ih0,    // [128,5]
    const float* __restrict__ w_hh0,    // [128,128]
    const float* __restrict__ b_ih0,    // [128]
    const float* __restrict__ b_hh0,    // [128]
    const float* __restrict__ w_ih1,    // [128,128]
    const float* __restrict__ w_hh1,    // [128,128]
    const float* __restrict__ b_ih1,    // [128]
    const float* __restrict__ b_hh1,    // [128]
    const float* __restrict__ w_out,    // [1,128]
    const float* __restrict__ b_out,    // [1]
    float* __restrict__ out)            // [204800 y] ++ [65536 final states]
{
    __shared__ __align__(16) float     x_lds[TIN * 8];   // fp32, 25.6 KB
    __shared__ __align__(16) float     xwr[32][HD];      // xw ring, 16 KB
    __shared__ __align__(16) _Float16  h0r[16][HD];      // h0 ring, 4 KB
    __shared__ __align__(16) _Float16  h1r[16][HD];      // h1 ring, 4 KB
    __shared__ __align__(16) float     Ar[16][HD];       // A ring, 8 KB
    __shared__ float y_lds[TIN];                         // 3.2 KB
    __shared__ int   prog[8];   // 0:e0 1:e1 2:e2 3:e3-y 4:xw-produced

    const int tid = threadIdx.x;
    const int bb  = blockIdx.x;
    const int wv  = tid >> 6;           // engine 0..3
    const int l   = tid & 63;
    const int qd  = l >> 2;             // row group: rows 8qd..8qd+7
    const int cc  = l & 3;              // col chunk: cols 32cc..32cc+31

    volatile int* vp = prog;

    if (tid < 8) prog[tid] = 0;
    for (int i = tid; i < TIN * NF; i += 256) {
        int t = i / 5, f = i - 5 * t;
        x_lds[t * 8 + f] = x[bb * (TIN * NF) + i];
    }
    if (tid < HD) {
        h0r[15][tid] = (_Float16)h_state[bb * HD + tid];
        h1r[15][tid] = (_Float16)h_state[BATCH * HD + bb * HD + tid];
    }

    // ---- resident weights ----
    h16x2 wreg[8][16];
    float bias[8];
    if (wv < 3) {
        const float* W = (wv == 0) ? w_hh0 : ((wv == 1) ? w_ih1 : w_hh1);
        #pragma unroll
        for (int j = 0; j < 8; ++j) {
            const float* rp = W + (8 * qd + j) * HD + 32 * cc;
            #pragma unroll
            for (int t = 0; t < 16; ++t) {
                h16x2 w2 = { (_Float16)rp[2 * t], (_Float16)rp[2 * t + 1] };
                wreg[j][t] = w2;
            }
            bias[j] = (wv == 0) ? (b_ih0[8 * qd + j] + b_hh0[8 * qd + j])
                    : (wv == 1) ? (b_ih1[8 * qd + j] + b_hh1[8 * qd + j]) : 0.f;
        }
    }
    float w0a[NF], w0b[NF], wo0 = 0.f, wo1 = 0.f;
    if (wv == 3) {
        #pragma unroll
        for (int f = 0; f < NF; ++f) {
            w0a[f] = w_ih0[l * NF + f];
            w0b[f] = w_ih0[(l + 64) * NF + f];
        }
        wo0 = w_out[2 * l]; wo1 = w_out[2 * l + 1];
    }
    const float bout = b_out[0];

    __syncthreads();

    #define WAITGE(idx, val) do { while (vp[idx] < (val)) {} \
        __asm__ __volatile__("" ::: "memory"); } while (0)
    #define PUBLISH(idx, val) do { __threadfence_block(); \
        if (l == 0) vp[idx] = (val); } while (0)

    // 128-fdot2 tile + quad allreduce; acc[j] = full dot for row 8qd+j.
    #define TILE_DOTS(HP, ACC) do {                                        \
        h16x8 q0 = *(const h16x8*)(HP);                                    \
        h16x8 q1 = *(const h16x8*)((HP) + 8);                              \
        h16x8 q2 = *(const h16x8*)((HP) + 16);                             \
        h16x8 q3 = *(const h16x8*)((HP) + 24);                             \
        h16x2 hh[16];                                                      \
        _Pragma("unroll")                                                  \
        for (int t = 0; t < 4; ++t) {                                      \
            hh[t]      = (h16x2){ q0[2*t], q0[2*t+1] };                    \
            hh[4 + t]  = (h16x2){ q1[2*t], q1[2*t+1] };                    \
            hh[8 + t]  = (h16x2){ q2[2*t], q2[2*t+1] };                    \
            hh[12 + t] = (h16x2){ q3[2*t], q3[2*t+1] };                    \
        }                                                                  \
        _Pragma("unroll")                                                  \
        for (int j = 0; j < 8; ++j) {                                      \
            float a0 = 0.f;                                                \
            _Pragma("unroll")                                              \
            for (int t = 0; t < 16; ++t)                                   \
                a0 = __builtin_amdgcn_fdot2(wreg[j][t], hh[t], a0, false); \
            ACC[j] = a0;                                                   \
        }                                                                  \
        _Pragma("unroll")                                                  \
        for (int j = 0; j < 8; ++j) ACC[j] += dpp_mov<0xB1>(ACC[j]);       \
        _Pragma("unroll")                                                  \
        for (int j = 0; j < 8; ++j) ACC[j] += dpp_mov<0x4E>(ACC[j]);       \
    } while (0)

    float fin[8];
    #pragma unroll
    for (int j = 0; j < 8; ++j) fin[j] = 0.f;

    if (wv == 0) {
        // ---- e0: h0 recurrence ----
        for (int s = 0; s < TT; ++s) {
            if (s >= 16 && (s & 7) == 0) WAITGE(1, s - 8);        // bp vs e1
            if (s < TIN && (s & 15) == 0) {                       // xw ready
                int need = s + 16; if (need > TIN) need = TIN;
                WAITGE(4, need);
            }
            float xw0[8];
            if (s < TIN) {
                f32x4v a = *(const f32x4v*)&xwr[s & 31][8 * qd];
                f32x4v b = *(const f32x4v*)&xwr[s & 31][8 * qd + 4];
                xw0[0]=a[0]; xw0[1]=a[1]; xw0[2]=a[2]; xw0[3]=a[3];
                xw0[4]=b[0]; xw0[5]=b[1]; xw0[6]=b[2]; xw0[7]=b[3];
            } else {
                #pragma unroll
                for (int j = 0; j < 8; ++j) xw0[j] = 0.f;
            }
            const _Float16* hp = &h0r[(s + 15) & 15][32 * cc];
            float acc[8];
            TILE_DOTS(hp, acc);
            float v[8];
            #pragma unroll
            for (int j = 0; j < 8; ++j)
                v[j] = fmaxf(acc[j] + bias[j] + xw0[j], 0.f);
            if (cc == 0) {
                h16x8 pk;
                #pragma unroll
                for (int j = 0; j < 8; ++j) pk[j] = (_Float16)v[j];
                *(h16x8*)&h0r[s & 15][8 * qd] = pk;
            }
            if (s == TT - 1) {
                #pragma unroll
                for (int j = 0; j < 8; ++j) fin[j] = v[j];
            }
            PUBLISH(0, s + 1);
        }
    } else if (wv == 1) {
        // ---- e1: A[t] = Wih1.h0[t] + b1 ----
        for (int t = 0; t < TT; ++t) {
            int c0 = vp[0];                                       // early read
            if (t >= 16 && (t & 7) == 0) WAITGE(2, t - 8);        // bp vs e2
            if (c0 < t + 1) WAITGE(0, t + 1);
            __asm__ __volatile__("" ::: "memory");
            const _Float16* hp = &h0r[t & 15][32 * cc];
            float acc[8];
            TILE_DOTS(hp, acc);
            if (cc == 0) {
                f32x4v f0 = { acc[0] + bias[0], acc[1] + bias[1],
                              acc[2] + bias[2], acc[3] + bias[3] };
                f32x4v f1 = { acc[4] + bias[4], acc[5] + bias[5],
                              acc[6] + bias[6], acc[7] + bias[7] };
                *(f32x4v*)&Ar[t & 15][8 * qd]     = f0;
                *(f32x4v*)&Ar[t & 15][8 * qd + 4] = f1;
            }
            PUBLISH(1, t + 1);
        }
    } else if (wv == 2) {
        // ---- e2: h1 recurrence ----
        for (int t = 0; t < TT; ++t) {
            int c1 = vp[1];
            if (t >= 16 && (t & 7) == 0) WAITGE(3, t - 8);        // bp vs e3
            if (c1 < t + 1) WAITGE(1, t + 1);
            __asm__ __volatile__("" ::: "memory");
            f32x4v a0 = *(const f32x4v*)&Ar[t & 15][8 * qd];
            f32x4v a1 = *(const f32x4v*)&Ar[t & 15][8 * qd + 4];
            const _Float16* hp = &h1r[(t + 15) & 15][32 * cc];
            float acc[8];
            TILE_DOTS(hp, acc);
            float v[8];
            v[0] = fmaxf(acc[0] + a0[0], 0.f);
            v[1] = fmaxf(acc[1] + a0[1], 0.f);
            v[2] = fmaxf(acc[2] + a0[2], 0.f);
            v[3] = fmaxf(acc[3] + a0[3], 0.f);
            v[4] = fmaxf(acc[4] + a1[0], 0.f);
            v[5] = fmaxf(acc[5] + a1[1], 0.f);
            v[6] = fmaxf(acc[6] + a1[2], 0.f);
            v[7] = fmaxf(acc[7] + a1[3], 0.f);
            if (cc == 0) {
                h16x8 pk;
                #pragma unroll
                for (int j = 0; j < 8; ++j) pk[j] = (_Float16)v[j];
                *(h16x8*)&h1r[t & 15][8 * qd] = pk;
            }
            if (t == TT - 1) {
                #pragma unroll
                for (int j = 0; j < 8; ++j) fin[j] = v[j];
            }
            PUBLISH(2, t + 1);
        }
    } else {
        // ---- e3: xw producer (24 ahead) + y-dots ----
        #define PRODUCE_XW(TTI) do {                                       \
            const float* xr = &x_lds[(TTI) * 8];                           \
            f32x4v xv = *(const f32x4v*)xr;                                \
            float x4 = xr[4];                                              \
            float xa = w0a[0]*xv[0] + w0a[1]*xv[1] + w0a[2]*xv[2]          \
                     + w0a[3]*xv[3] + w0a[4]*x4;                           \
            float xb = w0b[0]*xv[0] + w0b[1]*xv[1] + w0b[2]*xv[2]          \
                     + w0b[3]*xv[3] + w0b[4]*x4;                           \
            xwr[(TTI) & 31][l]      = xa;                                  \
            xwr[(TTI) & 31][l + 64] = xb;                                  \
            PUBLISH(4, (TTI) + 1);                                         \
        } while (0)
        for (int tt = 0; tt < 24; ++tt) PRODUCE_XW(tt);
        for (int t = 0; t < TIN; ++t) {
            const int tt = t + 24;
            if (tt < TIN) {
                if ((t & 7) == 0 && tt >= 32) WAITGE(0, tt - 24); // bp vs e0
                PRODUCE_XW(tt);
            }
            int c2 = vp[2];
            if (c2 < t + 1) WAITGE(2, t + 1);
            __asm__ __volatile__("" ::: "memory");
            union { unsigned u; h16x2 h; } hv;
            hv.u = *(const unsigned*)&h1r[t & 15][2 * l];
            float z = (float)hv.h[0] * wo0 + (float)hv.h[1] * wo1;
            z += __shfl_xor(z, 1, 64);
            z += __shfl_xor(z, 2, 64);
            z += __shfl_xor(z, 4, 64);
            z += __shfl_xor(z, 8, 64);
            z += __shfl_xor(z, 16, 64);
            z += __shfl_xor(z, 32, 64);
            if (l == 0) y_lds[t] = 1.f / (1.f + expf(-(z + bout)));
            PUBLISH(3, t + 1);
        }
        __threadfence_block();
        if (l == 0) vp[3] = 1000000;   // release e2's backpressure forever
    }

    __syncthreads();

    // ---- epilogue: single global dump ----
    for (int i = tid; i < TIN; i += 256)
        out[bb * TIN + i] = y_lds[i];
    if (wv == 0 && cc == 0) {
        #pragma unroll
        for (int j = 0; j < 8; ++j)
            out[TIN * BATCH + bb * HD + 8 * qd + j] = fin[j];
    }
    if (wv == 2 && cc == 0) {
        #pragma unroll
        for (int j = 0; j < 8; ++j)
            out[TIN * BATCH + BATCH * HD + bb * HD + 8 * qd + j] = fin[j];
    }
}

extern "C" void kernel_launch(void* const* d_in, const int* in_sizes, int n_in,
                              void* d_out, int out_size, void* d_ws, size_t ws_size,
                              hipStream_t stream) {
    (void)in_sizes; (void)n_in; (void)d_ws; (void)ws_size; (void)out_size;
    rnn_pipe<<<dim3(BATCH), dim3(256), 0, stream>>>(
        (const float*)d_in[0],  (const float*)d_in[1],
        (const float*)d_in[2],  (const float*)d_in[3],
        (const float*)d_in[4],  (const float*)d_in[5],
        (const float*)d_in[6],  (const float*)d_in[7],
        (const float*)d_in[8],  (const float*)d_in[9],
        (const float*)d_in[10], (const float*)d_in[11],
        (float*)d_out);
}

// Round 10
// 508.296 us; speedup vs baseline: 1.5806x; 1.3154x over previous
//
#include <hip/hip_runtime.h>
#include <math.h>

// 2-layer ReLU RNN, B=256, T=1000 (input 800 + zero pad), H=128, F=5.
// R10 = R7 (best: 527us; 768 thr = 3 matvec groups x 256, 8x8 tiles,
// XOR-linear row map, all-DPP 16-lane reduce, fdot2, 1 barrier/step) with
// the output path de-fattened:
//  - y-dots every 16 steps (ring depth 32), DPP-only reduction: removes the
//    6-chained-DS-shfl burst (~700 cyc on group 1 every 8th step) and the
//    scalar u16 reads (the 32K bank conflicts).
//  - x stored fp16 -> 3 fdot2 off one b128 read (was float4+f32 + 5 fmaf)
//    on g0's critical recurrence path.
//  - w_out in registers (fp16 pairs), wout_lds dropped.
// R9 lesson: >~100 resident regs/thread => compiler AGPR-shuffles (VGPR=140
// with 128-reg weight sets); keep per-thread weights at 32 regs (VGPR~40).

#define TT    1000
#define TIN   800
#define HD    128
#define NF    5
#define BATCH 256

typedef _Float16 h16x2 __attribute__((ext_vector_type(2)));
typedef _Float16 h16x8 __attribute__((ext_vector_type(8)));

template<int CTRL>
__device__ __forceinline__ float dpp_mov(float v) {
    union { float f; int i; } u, r;
    u.f = v;
    r.i = __builtin_amdgcn_update_dpp(0, u.i, CTRL, 0xF, 0xF, true);
    return r.f;
}

__global__ __launch_bounds__(768, 3) void rnn_dot2(
    const float* __restrict__ x,        // [256,800,5]
    const float* __restrict__ h_state,  // [2,256,128]
    const float* __restrict__ w_ih0,    // [128,5]
    const float* __restrict__ w_hh0,    // [128,128]
    const float* __restrict__ b_ih0,    // [128]
    const float* __restrict__ b_hh0,    // [128]
    const float* __restrict__ w_ih1,    // [128,128]
    const float* __restrict__ w_hh1,    // [128,128]
    const float* __restrict__ b_ih1,    // [128]
    const float* __restrict__ b_hh1,    // [128]
    const float* __restrict__ w_out,    // [1,128]
    const float* __restrict__ b_out,    // [1]
    float* __restrict__ out)            // [204800 y] ++ [65536 final states]
{
    __shared__ __align__(16) _Float16 x_h[TIN * 8];      // fp16, 12.8 KB
    __shared__ __align__(16) _Float16 h0h[2][HD];
    __shared__ __align__(16) _Float16 h1h[2][HD];
    __shared__ float A_f[2][HD];                         // fp32 pre-act
    __shared__ __align__(16) _Float16 ring[32][HD];      // h1 history, 8 KB
    __shared__ float y_lds[TIN];                         // 3.2 KB

    const int tid = threadIdx.x;
    const int bb  = blockIdx.x;         // batch element
    const int grp = tid >> 8;           // 0,1,2 : matvec engine
    const int lt  = tid & 255;
    const int c   = lt & 15;            // col chunk / reduction lane
    const int rg  = lt >> 4;            // row group (8 rows)
    const int g   = (4 * (c & 1)) ^ (2 * ((c >> 1) & 1)) ^ (7 * ((c >> 2) & 1));
    const int row = rg * 8 + g;         // row this thread finalizes
    const bool writer = (c & 8) == 0;

    // ---- stage x[bb] into LDS (fp16, stride 8, pads zero) ----
    for (int i = tid; i < TIN * 8; i += 768) x_h[i] = (_Float16)0.f;
    __syncthreads();
    for (int i = tid; i < TIN * NF; i += 768) {
        int t = i / 5, f = i - 5 * t;
        x_h[t * 8 + f] = (_Float16)x[bb * (TIN * NF) + i];
    }
    if (tid < HD) {
        h0h[0][tid] = (_Float16)h_state[bb * HD + tid];
        h1h[0][tid] = (_Float16)h_state[BATCH * HD + bb * HD + tid];
    }

    // ---- weights: my 8x8 tile, rows rg*8+(j^g), cols c*8..c*8+7, fp16 ----
    const float* Wsrc = (grp == 0) ? w_hh0 : ((grp == 1) ? w_ih1 : w_hh1);
    h16x2 wp[8][4];
    #pragma unroll
    for (int j = 0; j < 8; ++j) {
        const float* rp = Wsrc + (rg * 8 + (j ^ g)) * HD + c * 8;
        #pragma unroll
        for (int t = 0; t < 4; ++t) {
            h16x2 w2 = { (_Float16)rp[2 * t], (_Float16)rp[2 * t + 1] };
            wp[j][t] = w2;
        }
    }
    h16x2 wx0 = {0,0}, wx1 = {0,0}, wx2 = {0,0};   // g0: Wih0 row (fp16)
    h16x2 wo[4];                                    // g1: wout[l4*8..+7]
    float bias = 0.f;
    if (grp == 0) {
        wx0[0] = (_Float16)w_ih0[row * NF + 0];
        wx0[1] = (_Float16)w_ih0[row * NF + 1];
        wx1[0] = (_Float16)w_ih0[row * NF + 2];
        wx1[1] = (_Float16)w_ih0[row * NF + 3];
        wx2[0] = (_Float16)w_ih0[row * NF + 4];
        bias = b_ih0[row] + b_hh0[row];
    } else if (grp == 1) {
        const int l4 = lt & 15;
        #pragma unroll
        for (int t = 0; t < 4; ++t) {
            wo[t][0] = (_Float16)w_out[l4 * 8 + 2 * t];
            wo[t][1] = (_Float16)w_out[l4 * 8 + 2 * t + 1];
        }
        bias = 0.f;
    } else {
        bias = b_ih1[row] + b_hh1[row];
    }
    const float bout = b_out[0];

    float hfin = 0.f;   // grp0 writer: h0[999]; grp2 writer: h1[999]

    __syncthreads();

    // 8x8 tile matvec via fdot2 + all-DPP 16-lane reduction (R2/R7-verified).
    auto matvec = [&](const _Float16* hbuf) -> float {
        h16x8 hv = *(const h16x8*)(hbuf + c * 8);
        h16x2 hp0 = { hv[0], hv[1] }, hp1 = { hv[2], hv[3] };
        h16x2 hp2 = { hv[4], hv[5] }, hp3 = { hv[6], hv[7] };
        float a[8];
        #pragma unroll
        for (int j = 0; j < 8; ++j) {
            float aj;
            aj = __builtin_amdgcn_fdot2(wp[j][0], hp0, 0.f, false);
            aj = __builtin_amdgcn_fdot2(wp[j][1], hp1, aj,  false);
            aj = __builtin_amdgcn_fdot2(wp[j][2], hp2, aj,  false);
            aj = __builtin_amdgcn_fdot2(wp[j][3], hp3, aj,  false);
            a[j] = aj;
        }
        a[0] += dpp_mov<0xB1>(a[4]);   // xor1
        a[1] += dpp_mov<0xB1>(a[5]);
        a[2] += dpp_mov<0xB1>(a[6]);
        a[3] += dpp_mov<0xB1>(a[7]);
        a[0] += dpp_mov<0x4E>(a[2]);   // xor2
        a[1] += dpp_mov<0x4E>(a[3]);
        a[0] += dpp_mov<0x140>(a[1]);  // xor15 (row_mirror)
        a[0] += dpp_mov<0x128>(a[0]);  // xor8  (row_ror:8)
        return a[0];
    };

    #pragma unroll 2
    for (int s = 0; s < TT + 2; ++s) {
        const int p = s & 1;
        const int q = p ^ 1;

        if (grp == 0) {
            // h0[s] = relu(Whh0.h0[s-1] + Wih0.x[s] + b)
            if (s < TT) {
                float acc = matvec(h0h[p]);
                float v = acc + bias;
                if (s < TIN) {
                    h16x8 xv = *(const h16x8*)(&x_h[s * 8]);
                    h16x2 xp0 = { xv[0], xv[1] }, xp1 = { xv[2], xv[3] };
                    h16x2 xp2 = { xv[4], xv[5] };
                    float xc = __builtin_amdgcn_fdot2(wx2, xp2, 0.f, false);
                    xc = __builtin_amdgcn_fdot2(wx1, xp1, xc, false);
                    xc = __builtin_amdgcn_fdot2(wx0, xp0, xc, false);
                    v += xc;
                }
                v = fmaxf(v, 0.f);
                if (writer) {
                    h0h[q][row] = (_Float16)v;
                    if (s == TT - 1) hfin = v;
                }
            }
        } else if (grp == 1) {
            // A[s-1] = Wih1 . h0[s-1]  (fp32)
            if (s <= TT) {
                float acc = matvec(h0h[p]);
                if (writer) A_f[q][row] = acc;
            }
            // y-dots every 16 steps: 16 slots x 16 lanes, DPP-only reduce
            if (s >= 18 && s <= 818 && ((s - 2) & 15) == 0) {
                const int u  = (s - 33) + (lt >> 4);   // slot = lt>>4
                const int l4 = lt & 15;
                if (u >= 0 && u < TIN) {
                    h16x8 hv = *(const h16x8*)(&ring[u & 31][l4 * 8]);
                    h16x2 hp0 = { hv[0], hv[1] }, hp1 = { hv[2], hv[3] };
                    h16x2 hp2 = { hv[4], hv[5] }, hp3 = { hv[6], hv[7] };
                    float z;
                    z = __builtin_amdgcn_fdot2(wo[0], hp0, 0.f, false);
                    z = __builtin_amdgcn_fdot2(wo[1], hp1, z,  false);
                    z = __builtin_amdgcn_fdot2(wo[2], hp2, z,  false);
                    z = __builtin_amdgcn_fdot2(wo[3], hp3, z,  false);
                    z += dpp_mov<0xB1>(z);    // xor1
                    z += dpp_mov<0x4E>(z);    // xor2
                    z += dpp_mov<0x140>(z);   // xor15
                    z += dpp_mov<0x128>(z);   // xor8
                    if (l4 == 0) y_lds[u] = 1.f / (1.f + expf(-(z + bout)));
                }
            }
        } else {
            // h1[s-2] = relu(A[s-2] + Whh1.h1[s-3] + b)
            if (s >= 2) {
                const int u = s - 2;
                float acc = matvec(h1h[p]);
                float v = fmaxf(acc + bias + A_f[p][row], 0.f);
                if (writer) {
                    _Float16 vh = (_Float16)v;
                    h1h[q][row] = vh;
                    if (u < TIN) ring[u & 31][row] = vh;
                    if (u == TT - 1) hfin = v;
                }
            }
        }
        __syncthreads();
    }

    // ---- epilogue: single global dump ----
    for (int i = tid; i < TIN; i += 768)
        out[bb * TIN + i] = y_lds[i];
    if (grp == 0 && writer)
        out[TIN * BATCH + bb * HD + row] = hfin;
    if (grp == 2 && writer)
        out[TIN * BATCH + BATCH * HD + bb * HD + row] = hfin;
}

extern "C" void kernel_launch(void* const* d_in, const int* in_sizes, int n_in,
                              void* d_out, int out_size, void* d_ws, size_t ws_size,
                              hipStream_t stream) {
    (void)in_sizes; (void)n_in; (void)d_ws; (void)ws_size; (void)out_size;
    rnn_dot2<<<dim3(BATCH), dim3(768), 0, stream>>>(
        (const float*)d_in[0],  (const float*)d_in[1],
        (const float*)d_in[2],  (const float*)d_in[3],
        (const float*)d_in[4],  (const float*)d_in[5],
        (const float*)d_in[6],  (const float*)d_in[7],
        (const float*)d_in[8],  (const float*)d_in[9],
        (const float*)d_in[10], (const float*)d_in[11],
        (float*)d_out);
}